// Round 10
// baseline (3368.121 us; speedup 1.0000x reference)
//
#include <hip/hip_runtime.h>
#include <hip/hip_bf16.h>
#include <cstdint>
#include <cstddef>

// Model_69647189672235: GRU encoder-decoder w/ attention pooling.
// B=256 T=256 D=72 HID=512 H=1024, to_predict=10 (hardcoded; scalar input ignored).
// R12: spend enc_fused producer slack. Sync protocol untouched (4 topologies all
// measured 8.6-8.9us/step -> turnaround constant is structural; only a protocol-
// structure change could move it, deferred). Changes: (1) launch tc>=1 producers
// also compute score tiles for chunk tc-1 (2 extra 128^2 tiles/wg in measured
// slack); only chunk 7's score runs standalone. (2) tc=7's fully-idle producers
// convert decoder weights. (3) logits_red fused into attention.
// R11 = 3242us (enc 8x276 + ~1030 tail). Predicted ~3080us; absmax unchanged.

using bf16 = __hip_bfloat16;
typedef __attribute__((ext_vector_type(8))) short short8;
typedef __attribute__((ext_vector_type(4))) short s4_t;
typedef __attribute__((ext_vector_type(4))) float floatx4;

#define B_    256
#define T_    256
#define D_    72
#define DP_   96      // D padded to mult of 32 for BK=32
#define HID_  512
#define H_    1024
#define H3_   3072
#define NPRED 10
#define CHUNK 32      // encoder timesteps per persistent launch
#define RA    16384   // rows per slab in chunked par2lat GEMMs

__device__ __forceinline__ float b2f(bf16 v){ return __bfloat162float(v); }
__device__ __forceinline__ bf16  f2b(float v){ return __float2bfloat16(v); }

__device__ __forceinline__ void async_ld16(const bf16* g, bf16* l) {
  __builtin_amdgcn_global_load_lds(
      (const __attribute__((address_space(1))) unsigned int*)g,
      (__attribute__((address_space(3))) unsigned int*)l,
      16, 0, 0);
}

// Cached 16B load; asm keeps it below the poll and countable by vmcnt.
__device__ __forceinline__ short8 load16_cached(const bf16* p) {
  short8 r;
  asm volatile("global_load_dwordx4 %0, %1, off"
               : "=v"(r) : "v"(p) : "memory");
  return r;
}
// LLC write-through 8B store for cross-XCD visibility of h.
__device__ __forceinline__ void store8_llc(bf16* p, s4_t v) {
  asm volatile("global_store_dwordx2 %0, %1, off sc0 sc1"
               :: "v"(p), "v"(v) : "memory");
}

enum { EPI_F32 = 0, EPI_BF16 = 1, EPI_BF16_RELU = 2, EPI_BF16_RELU_PERM = 3 };

// C = epi(A @ B^T + bias). A:[M,K] bf16 row-major, B:[N,K] bf16 row-major.
template<int BM, int BN, int WM, int WN, int EPI>
__global__ __launch_bounds__(256, 2) void gemm_bt(
    const bf16* __restrict__ A, const bf16* __restrict__ B,
    const float* __restrict__ bias, void* __restrict__ Cout,
    int M, int N, int K, int row_off)
{
  constexpr int BK = 32;
  constexpr int NWN = BN / WN;
  constexpr int MT = WM / 16, NT = WN / 16;
  constexpr int ASEG = BM * 4;
  constexpr int TSEG = (BM + BN) * 4;
  static_assert((BM/WM)*(BN/WN) == 4, "4 waves");
  static_assert(TSEG % 256 == 0, "uniform staging");

  __shared__ __align__(16) bf16 smem[(BM + BN) * BK];
  bf16* As = smem;
  bf16* Bs = smem + BM * BK;

  const int tid  = threadIdx.x;
  const int lane = tid & 63;
  const int wave = tid >> 6;
  const int wm = wave / NWN, wn = wave % NWN;
  const int m0 = blockIdx.y * BM, n0 = blockIdx.x * BN;

  floatx4 acc[MT][NT];
#pragma unroll
  for (int i = 0; i < MT; i++)
#pragma unroll
    for (int j = 0; j < NT; j++)
      acc[i][j] = floatx4{0.f, 0.f, 0.f, 0.f};

  const int krow = (lane >> 4) << 3;
  const int r16  = lane & 15;

  for (int k0 = 0; k0 < K; k0 += BK) {
    __syncthreads();
#pragma unroll
    for (int it = 0; it < TSEG / 256; it++) {
      int s = tid + it * 256;
      const bf16* g;
      if (s < ASEG) {
        int row = s >> 2, kseg = s & 3;
        g = A + (size_t)(m0 + row) * K + k0 + kseg * 8;
      } else {
        int s2 = s - ASEG;
        int row = s2 >> 2, kseg = s2 & 3;
        g = B + (size_t)(n0 + row) * K + k0 + kseg * 8;
      }
      async_ld16(g, smem + (size_t)s * 8);
    }
    __syncthreads();
    short8 af[MT], bfr[NT];
#pragma unroll
    for (int i = 0; i < MT; i++)
      af[i] = *(const short8*)(As + (wm * WM + i * 16 + r16) * BK + krow);
#pragma unroll
    for (int j = 0; j < NT; j++)
      bfr[j] = *(const short8*)(Bs + (wn * WN + j * 16 + r16) * BK + krow);
#pragma unroll
    for (int i = 0; i < MT; i++)
#pragma unroll
      for (int j = 0; j < NT; j++)
        acc[i][j] = __builtin_amdgcn_mfma_f32_16x16x32_bf16(af[i], bfr[j], acc[i][j], 0, 0, 0);
  }

#pragma unroll
  for (int i = 0; i < MT; i++) {
#pragma unroll
    for (int j = 0; j < NT; j++) {
      int gn = n0 + wn * WN + j * 16 + r16;
      float bv = bias ? bias[gn] : 0.f;
#pragma unroll
      for (int r = 0; r < 4; r++) {
        int gm = m0 + wm * WM + i * 16 + ((lane >> 4) << 2) + r;
        float v = acc[i][j][r] + bv;
        if (EPI == EPI_BF16_RELU || EPI == EPI_BF16_RELU_PERM) v = fmaxf(v, 0.f);
        size_t orow;
        if (EPI == EPI_BF16_RELU_PERM) {
          int g = row_off + gm;
          orow = (size_t)(g & 255) * 256 + (size_t)(g >> 8);
        } else {
          orow = (size_t)gm;
        }
        if (EPI == EPI_F32) ((float*)Cout)[orow * (size_t)N + gn] = v;
        else                ((bf16*) Cout)[orow * (size_t)N + gn] = f2b(v);
      }
    }
  }
}

// Dual GEMM (two independent 64x128-tile EPI_F32 GEMMs selected by blockIdx.z).
__global__ __launch_bounds__(256, 2) void gemm_bt_dual(
    const bf16* __restrict__ A0, const bf16* __restrict__ B0,
    const float* __restrict__ bias0, float* __restrict__ C0,
    const bf16* __restrict__ A1, const bf16* __restrict__ B1,
    const float* __restrict__ bias1, float* __restrict__ C1,
    int M, int N, int K)
{
  constexpr int BM = 64, BN = 128, BK = 32;
  constexpr int ASEG = BM * 4, TSEG = (BM + BN) * 4;
  const bf16* A = blockIdx.z ? A1 : A0;
  const bf16* B = blockIdx.z ? B1 : B0;
  const float* bias = blockIdx.z ? bias1 : bias0;
  float* Cout = blockIdx.z ? C1 : C0;

  __shared__ __align__(16) bf16 smem[(BM + BN) * BK];
  bf16* As = smem;
  bf16* Bs = smem + BM * BK;

  const int tid  = threadIdx.x;
  const int lane = tid & 63;
  const int wave = tid >> 6;
  const int wm = wave >> 1, wn = wave & 1;   // WM=32, WN=64 -> MT=2, NT=4
  const int m0 = blockIdx.y * BM, n0 = blockIdx.x * BN;

  floatx4 acc[2][4];
#pragma unroll
  for (int i = 0; i < 2; i++)
#pragma unroll
    for (int j = 0; j < 4; j++)
      acc[i][j] = floatx4{0.f, 0.f, 0.f, 0.f};

  const int krow = (lane >> 4) << 3;
  const int r16  = lane & 15;

  for (int k0 = 0; k0 < K; k0 += BK) {
    __syncthreads();
#pragma unroll
    for (int it = 0; it < TSEG / 256; it++) {
      int s = tid + it * 256;
      const bf16* g;
      if (s < ASEG) {
        int row = s >> 2, kseg = s & 3;
        g = A + (size_t)(m0 + row) * K + k0 + kseg * 8;
      } else {
        int s2 = s - ASEG;
        int row = s2 >> 2, kseg = s2 & 3;
        g = B + (size_t)(n0 + row) * K + k0 + kseg * 8;
      }
      async_ld16(g, smem + (size_t)s * 8);
    }
    __syncthreads();
    short8 af[2], bfr[4];
#pragma unroll
    for (int i = 0; i < 2; i++)
      af[i] = *(const short8*)(As + (wm * 32 + i * 16 + r16) * BK + krow);
#pragma unroll
    for (int j = 0; j < 4; j++)
      bfr[j] = *(const short8*)(Bs + (wn * 64 + j * 16 + r16) * BK + krow);
#pragma unroll
    for (int i = 0; i < 2; i++)
#pragma unroll
      for (int j = 0; j < 4; j++)
        acc[i][j] = __builtin_amdgcn_mfma_f32_16x16x32_bf16(af[i], bfr[j], acc[i][j], 0, 0, 0);
  }

#pragma unroll
  for (int i = 0; i < 2; i++)
#pragma unroll
    for (int j = 0; j < 4; j++) {
      int gn = n0 + wn * 64 + j * 16 + r16;
      float bv = bias[gn];
#pragma unroll
      for (int r = 0; r < 4; r++) {
        int gm = m0 + wm * 32 + i * 16 + ((lane >> 4) << 2) + r;
        Cout[(size_t)gm * N + gn] = acc[i][j][r] + bv;
      }
    }
}

// One 128x128 score tile: part[m0+row][n0>>7] = sum_{gn in block}
//   relu(enc_out[row,:] . l2s_w1[gn,:] + b1[gn]) * w2[gn]
// Deterministic (unique-writer partials). smem needs 16KB GEMM + 16.9KB pl.
__device__ __forceinline__ void score_tile(
    char* sm, const bf16* __restrict__ A, const bf16* __restrict__ Bw,
    const float* __restrict__ b1, const float* __restrict__ w2,
    float* __restrict__ part, size_t m0, int n0, int tid)
{
  constexpr int BK = 32;
  bf16* As = (bf16*)sm;
  bf16* Bs = As + 128 * BK;
  float* pl = (float*)(sm + 16384);   // [128][33]

  const int lane = tid & 63;
  const int wave = tid >> 6;
  const int wm = wave >> 1, wn = wave & 1;   // 2x2 waves, WM=WN=64
  const int krow = (lane >> 4) << 3;
  const int r16  = lane & 15;
  const int kq   = lane >> 4;

  floatx4 acc[4][4];
#pragma unroll
  for (int i = 0; i < 4; i++)
#pragma unroll
    for (int j = 0; j < 4; j++)
      acc[i][j] = floatx4{0.f, 0.f, 0.f, 0.f};

  for (int k0 = 0; k0 < H_; k0 += BK) {
    __syncthreads();
#pragma unroll
    for (int it = 0; it < 4; it++) {
      int s = tid + it * 256;
      const bf16* g;
      if (s < 512) {
        int row = s >> 2, kseg = s & 3;
        g = A + (m0 + row) * H_ + k0 + kseg * 8;
      } else {
        int s2 = s - 512;
        int row = s2 >> 2, kseg = s2 & 3;
        g = Bw + (size_t)(n0 + row) * H_ + k0 + kseg * 8;
      }
      async_ld16(g, As + (size_t)s * 8);
    }
    __syncthreads();
    short8 af[4], bfr[4];
#pragma unroll
    for (int i = 0; i < 4; i++)
      af[i] = *(const short8*)(As + (wm * 64 + i * 16 + r16) * BK + krow);
#pragma unroll
    for (int j = 0; j < 4; j++)
      bfr[j] = *(const short8*)(Bs + (wn * 64 + j * 16 + r16) * BK + krow);
#pragma unroll
    for (int i = 0; i < 4; i++)
#pragma unroll
      for (int j = 0; j < 4; j++)
        acc[i][j] = __builtin_amdgcn_mfma_f32_16x16x32_bf16(af[i], bfr[j], acc[i][j], 0, 0, 0);
  }

#pragma unroll
  for (int i = 0; i < 4; i++) {
#pragma unroll
    for (int r = 0; r < 4; r++) {
      int row = wm * 64 + i * 16 + kq * 4 + r;
      float s = 0.f;
#pragma unroll
      for (int j = 0; j < 4; j++) {
        int gn = n0 + wn * 64 + j * 16 + r16;
        s += fmaxf(acc[i][j][r] + b1[gn], 0.f) * w2[gn];
      }
      pl[row * 33 + wn * 16 + r16] = s;
    }
  }
  __syncthreads();
  if (tid < 128) {
    float t = 0.f;
#pragma unroll
    for (int c = 0; c < 32; c++) t += pl[tid * 33 + c];
    part[(m0 + tid) * 4 + (n0 >> 7)] = t;
  }
  __syncthreads();
}

// standalone score (chunk 7 only): grid (4, 64)
__global__ __launch_bounds__(256, 2) void score_gemm(
    const bf16* __restrict__ A, const bf16* __restrict__ Bw,
    const float* __restrict__ b1, const float* __restrict__ w2,
    float* __restrict__ part, int m_off)
{
  __shared__ __align__(16) char sbuf[33536];
  score_tile(sbuf, A, Bw, b1, w2, part,
             (size_t)m_off + (size_t)blockIdx.y * 128, blockIdx.x * 128,
             threadIdx.x);
}

// fp32 -> bf16 with K padding (kout >= kin, pad zeros)
__global__ void convert_pad(const float* __restrict__ in, bf16* __restrict__ out,
                            int rows, int kin, int kout)
{
  size_t idx = (size_t)blockIdx.x * blockDim.x + threadIdx.x;
  if (idx >= (size_t)rows * kout) return;
  int r = idx / kout, c = idx % kout;
  out[idx] = (c < kin) ? f2b(in[(size_t)r * kin + c]) : f2b(0.f);
}

// zero h32 master + flags
__global__ void enc_init(float* __restrict__ h32, unsigned* __restrict__ bar)
{
  int idx = blockIdx.x * blockDim.x + threadIdx.x;
  h32[idx] = 0.f;
  if (idx < 512) bar[idx] = 0u;
}

// ppad[b][0:72] = bf16(x[b, T-1, :]), rest 0
__global__ void ppad_init(const float* __restrict__ x, bf16* __restrict__ ppad)
{
  int idx = blockIdx.x * blockDim.x + threadIdx.x;
  int b = idx / DP_, c = idx % DP_;
  float v = (c < D_) ? x[((size_t)b * T_ + (T_ - 1)) * D_ + c] : 0.f;
  ppad[idx] = f2b(v);
}

__device__ __forceinline__ float sigm(float v){ return 1.f / (1.f + __expf(-v)); }

// ---------------- fused encoder: recurrence + producer (xp, score, converts) --------
// wgs 0..127 recurrence: unchanged from R11 (proven): 32 h-cols/wg (16 LDS +
// 16 reg weights), k-split waves, 2-pass P reduce, 8-flag quarter poll,
// sc0|sc1 h stores, cached h loads.
// wgs 128..255 producer, three phases: (1) xp tiles for chunk tc+1 (if any);
// (2) score tiles for chunk tc-1 (if tc>=1): 2 x 128^2 tiles/wg into part;
// (3) tc==7 only: convert decoder weights fp32->bf16.
#define ENC_SMEM (98304 + 4*64*52*4)   // 96KB weights + 52-padded P = 151552 B
static_assert(ENC_SMEM <= 160*1024, "LDS");
static_assert(ENC_SMEM >= 33536, "producer score smem fits");

__global__ __launch_bounds__(256, 1) void enc_fused(
    const bf16* __restrict__ xpc_cur,  // [CHUNK*B, 3H] this chunk's gi (bih included)
    const bf16* __restrict__ whh,      // [3H, H]
    const float* __restrict__ bhh,     // [3H]
    bf16* __restrict__ enc_out,        // [T*B, H] t-major h16 history
    float* __restrict__ h32g,          // [B, H] fp32 master (chunk handoff)
    unsigned* __restrict__ bar,        // flags[4][32]
    int t0,
    const bf16* __restrict__ lat_nxt,  // latent slab for chunk tc+1
    const bf16* __restrict__ wih,      // [3H, H]
    const float* __restrict__ bih,     // [3H]
    bf16* __restrict__ xpc_nxt,        // [CHUNK*B, 3H] or null (tc==7)
    const bf16* __restrict__ sw1,      // l2s_w1 bf16 [512,1024]
    const float* __restrict__ sb1,     // l2s_b1
    const float* __restrict__ sw2,     // l2s_w2
    float* __restrict__ part,          // [T*B, 4]
    const float* __restrict__ dwih_f,  // dec_wih fp32 (tc==7 else null)
    const float* __restrict__ dwhh_f,
    bf16* __restrict__ dwih_b,
    bf16* __restrict__ dwhh_b)
{
  extern __shared__ char smem[];
  const int tid  = threadIdx.x;
  const int lane = tid & 63;
  const int wave = tid >> 6;
  const int wg   = blockIdx.x;
  const int r16  = lane & 15;
  const int kq   = lane >> 4;

  if (wg < 128) {
    // ================= recurrence (unchanged from R11) =================
    float* P = (float*)(smem + 98304);
    constexpr int PS = 52;

    const int rgrp = wg >> 5;
    const int rowb = rgrp * 64;
    const int j0   = (wg & 31) * 32;
    const int kb0  = wave * 256;

    unsigned* flagp  = bar + rgrp * 32 + wave * 8 + (lane & 7);
    unsigned* myflag = bar + rgrp * 32 + (wg & 31);

    for (int ci = tid; ci < 48 * 128; ci += 256) {
      int wrow = ci >> 7, kslot = ci & 127;
      int g = wrow >> 4, jj = wrow & 15;
      short8 v = *(const short8*)(whh + ((size_t)(g * H_ + j0 + jj)) * H_ + kslot * 8);
      *(short8*)(smem + kslot * 768 + wrow * 16) = v;
    }
    short8 rw[8][3];
#pragma unroll
    for (int it = 0; it < 8; it++)
#pragma unroll
      for (int g = 0; g < 3; g++)
        rw[it][g] = *(const short8*)(whh + ((size_t)(g * H_ + j0 + 16 + r16)) * H_
                                     + kb0 + it * 32 + kq * 8);

    const int row_loc = tid >> 2;
    const int cq      = tid & 3;
    const int b       = rowb + row_loc;
    const int jb0     = j0 + cq * 4;
    const int jb1     = j0 + 16 + cq * 4;

    floatx4 h32r0 = *(const floatx4*)(h32g + (size_t)b * H_ + jb0);
    floatx4 h32r1 = *(const floatx4*)(h32g + (size_t)b * H_ + jb1);
    const floatx4 bhr0 = *(const floatx4*)(bhh + jb0);
    const floatx4 bhz0 = *(const floatx4*)(bhh + H_ + jb0);
    const floatx4 bhn0 = *(const floatx4*)(bhh + 2 * H_ + jb0);
    const floatx4 bhr1 = *(const floatx4*)(bhh + jb1);
    const floatx4 bhz1 = *(const floatx4*)(bhh + H_ + jb1);
    const floatx4 bhn1 = *(const floatx4*)(bhh + 2 * H_ + jb1);

    __syncthreads();

#define ISSUE(IT)                                                              \
    {                                                                          \
      _Pragma("unroll")                                                        \
      for (int rf = 0; rf < 4; rf++)                                           \
        a[(IT) & 3][rf] = load16_cached(hsrc + (size_t)(rowb + rf * 16 + r16) * H_ \
                                        + kb0 + (IT) * 32 + kq * 8);           \
    }
#define GRP(IT, WC)                                                            \
    do {                                                                       \
      const char* bb = smem + (wave * 32 + (IT) * 4 + kq) * 768 + r16 * 16;    \
      short8 bw0 = *(const short8*)(bb);                                       \
      short8 bw1 = *(const short8*)(bb + 256);                                 \
      short8 bw2 = *(const short8*)(bb + 512);                                 \
      asm volatile("s_waitcnt vmcnt(" #WC ")" ::: "memory");                   \
      __builtin_amdgcn_sched_barrier(0);                                       \
      _Pragma("unroll")                                                        \
      for (int rf = 0; rf < 4; rf++) {                                         \
        accA[rf][0] = __builtin_amdgcn_mfma_f32_16x16x32_bf16(a[(IT)&3][rf], bw0, accA[rf][0], 0, 0, 0); \
        accA[rf][1] = __builtin_amdgcn_mfma_f32_16x16x32_bf16(a[(IT)&3][rf], bw1, accA[rf][1], 0, 0, 0); \
        accA[rf][2] = __builtin_amdgcn_mfma_f32_16x16x32_bf16(a[(IT)&3][rf], bw2, accA[rf][2], 0, 0, 0); \
        accB[rf][0] = __builtin_amdgcn_mfma_f32_16x16x32_bf16(a[(IT)&3][rf], rw[IT][0], accB[rf][0], 0, 0, 0); \
        accB[rf][1] = __builtin_amdgcn_mfma_f32_16x16x32_bf16(a[(IT)&3][rf], rw[IT][1], accB[rf][1], 0, 0, 0); \
        accB[rf][2] = __builtin_amdgcn_mfma_f32_16x16x32_bf16(a[(IT)&3][rf], rw[IT][2], accB[rf][2], 0, 0, 0); \
      }                                                                        \
      if ((IT) + 4 < 8) ISSUE((IT) + 4)                                        \
    } while (0)

    for (int ts = 0; ts < CHUNK; ts++) {
      const int tg = t0 + ts;

      const bf16* gi = xpc_cur + ((size_t)ts * B_ + b) * H3_;
      s4_t vr0 = *(const s4_t*)(gi + jb0);
      s4_t vz0 = *(const s4_t*)(gi + H_ + jb0);
      s4_t vn0 = *(const s4_t*)(gi + 2 * H_ + jb0);
      s4_t vr1 = *(const s4_t*)(gi + jb1);
      s4_t vz1 = *(const s4_t*)(gi + H_ + jb1);
      s4_t vn1 = *(const s4_t*)(gi + 2 * H_ + jb1);

      floatx4 accA[4][3], accB[4][3];
#pragma unroll
      for (int rf = 0; rf < 4; rf++)
#pragma unroll
        for (int g = 0; g < 3; g++) {
          accA[rf][g] = floatx4{0.f, 0.f, 0.f, 0.f};
          accB[rf][g] = floatx4{0.f, 0.f, 0.f, 0.f};
        }

      if (tg > 0) {
        const unsigned tgt = (unsigned)tg;
        while (1) {
          unsigned f;
          asm volatile("global_load_dword %0, %1, off sc0 sc1"
                       : "=v"(f) : "v"(flagp) : "memory");
          asm volatile("s_waitcnt vmcnt(0)" ::: "memory");
          if (__all((int)(f >= tgt))) break;
          __builtin_amdgcn_s_sleep(2);
        }
        const bf16* hsrc = enc_out + (size_t)(tg - 1) * B_ * H_;
        short8 a[4][4];
        ISSUE(0) ISSUE(1) ISSUE(2) ISSUE(3)
        GRP(0, 12); GRP(1, 12); GRP(2, 12); GRP(3, 12);
        GRP(4, 12); GRP(5,  8); GRP(6,  4); GRP(7,  0);
      }

      // pass 0: cols j0..j0+16
#pragma unroll
      for (int rf = 0; rf < 4; rf++)
#pragma unroll
        for (int g = 0; g < 3; g++)
#pragma unroll
          for (int rr = 0; rr < 4; rr++)
            P[(wave * 64 + rf * 16 + kq * 4 + rr) * PS + g * 16 + r16] = accA[rf][g][rr];
      __syncthreads();
      {
        const float* Pr = P + row_loc * PS + cq * 4;
        floatx4 sr4 = floatx4{0.f,0.f,0.f,0.f};
        floatx4 sz4 = floatx4{0.f,0.f,0.f,0.f};
        floatx4 sn4 = floatx4{0.f,0.f,0.f,0.f};
#pragma unroll
        for (int w = 0; w < 4; w++) {
          const float* pp = Pr + w * 64 * PS;
          sr4 += *(const floatx4*)(pp);
          sz4 += *(const floatx4*)(pp + 16);
          sn4 += *(const floatx4*)(pp + 32);
        }
        s4_t outv;
#pragma unroll
        for (int cc = 0; cc < 4; cc++) {
          float xr = __uint_as_float(((unsigned)(unsigned short)vr0[cc]) << 16);
          float xz = __uint_as_float(((unsigned)(unsigned short)vz0[cc]) << 16);
          float xn = __uint_as_float(((unsigned)(unsigned short)vn0[cc]) << 16);
          float rg = sigm(xr + sr4[cc] + bhr0[cc]);
          float zg = sigm(xz + sz4[cc] + bhz0[cc]);
          float ng = tanhf(xn + rg * (sn4[cc] + bhn0[cc]));
          float hnew = (1.f - zg) * ng + zg * h32r0[cc];
          h32r0[cc] = hnew;
          outv[cc] = (short)__builtin_bit_cast(unsigned short, f2b(hnew));
        }
        store8_llc(enc_out + ((size_t)tg * B_ + b) * H_ + jb0, outv);
      }
      __syncthreads();

      // pass 1: cols j0+16..j0+32
#pragma unroll
      for (int rf = 0; rf < 4; rf++)
#pragma unroll
        for (int g = 0; g < 3; g++)
#pragma unroll
          for (int rr = 0; rr < 4; rr++)
            P[(wave * 64 + rf * 16 + kq * 4 + rr) * PS + g * 16 + r16] = accB[rf][g][rr];
      __syncthreads();
      {
        const float* Pr = P + row_loc * PS + cq * 4;
        floatx4 sr4 = floatx4{0.f,0.f,0.f,0.f};
        floatx4 sz4 = floatx4{0.f,0.f,0.f,0.f};
        floatx4 sn4 = floatx4{0.f,0.f,0.f,0.f};
#pragma unroll
        for (int w = 0; w < 4; w++) {
          const float* pp = Pr + w * 64 * PS;
          sr4 += *(const floatx4*)(pp);
          sz4 += *(const floatx4*)(pp + 16);
          sn4 += *(const floatx4*)(pp + 32);
        }
        s4_t outv;
#pragma unroll
        for (int cc = 0; cc < 4; cc++) {
          float xr = __uint_as_float(((unsigned)(unsigned short)vr1[cc]) << 16);
          float xz = __uint_as_float(((unsigned)(unsigned short)vz1[cc]) << 16);
          float xn = __uint_as_float(((unsigned)(unsigned short)vn1[cc]) << 16);
          float rg = sigm(xr + sr4[cc] + bhr1[cc]);
          float zg = sigm(xz + sz4[cc] + bhz1[cc]);
          float ng = tanhf(xn + rg * (sn4[cc] + bhn1[cc]));
          float hnew = (1.f - zg) * ng + zg * h32r1[cc];
          h32r1[cc] = hnew;
          outv[cc] = (short)__builtin_bit_cast(unsigned short, f2b(hnew));
        }
        store8_llc(enc_out + ((size_t)tg * B_ + b) * H_ + jb1, outv);
      }

      asm volatile("s_waitcnt vmcnt(0)" ::: "memory");
      __syncthreads();
      if (tid == 0) {
        unsigned v = (unsigned)(tg + 1);
        asm volatile("global_store_dword %0, %1, off sc0 sc1"
                     :: "v"(myflag), "v"(v) : "memory");
      }
    }
#undef GRP
#undef ISSUE

    *(floatx4*)(h32g + (size_t)b * H_ + jb0) = h32r0;
    *(floatx4*)(h32g + (size_t)b * H_ + jb1) = h32r1;

  } else {
    // ================= producer =================
    const int p = wg - 128;

    // Phase 1: xp tiles for chunk tc+1
    if (xpc_nxt != nullptr) {
      const int wm = wave >> 1, wn = wave & 1;
      bf16* As = (bf16*)smem;
      bf16* Bs = As + 128 * 32;
      const int krow = kq << 3;

      for (int tile = 0; tile < 12; tile++) {
        const int t  = p + tile * 128;           // 64 x 24 tiles of 128^2
        const int m0 = (t / 24) * 128;
        const int n0 = (t % 24) * 128;

        floatx4 acc[4][4];
#pragma unroll
        for (int i = 0; i < 4; i++)
#pragma unroll
          for (int j = 0; j < 4; j++)
            acc[i][j] = floatx4{0.f, 0.f, 0.f, 0.f};

        for (int k0 = 0; k0 < H_; k0 += 32) {
          __syncthreads();
#pragma unroll
          for (int it = 0; it < 4; it++) {
            int s = tid + it * 256;
            const bf16* g;
            if (s < 512) {
              int row = s >> 2, kseg = s & 3;
              g = lat_nxt + (size_t)(m0 + row) * H_ + k0 + kseg * 8;
            } else {
              int s2 = s - 512;
              int row = s2 >> 2, kseg = s2 & 3;
              g = wih + (size_t)(n0 + row) * H_ + k0 + kseg * 8;
            }
            async_ld16(g, (bf16*)smem + (size_t)s * 8);
          }
          __syncthreads();
          short8 af[4], bfr[4];
#pragma unroll
          for (int i = 0; i < 4; i++)
            af[i] = *(const short8*)(As + (wm * 64 + i * 16 + r16) * 32 + krow);
#pragma unroll
          for (int j = 0; j < 4; j++)
            bfr[j] = *(const short8*)(Bs + (wn * 64 + j * 16 + r16) * 32 + krow);
#pragma unroll
          for (int i = 0; i < 4; i++)
#pragma unroll
            for (int j = 0; j < 4; j++)
              acc[i][j] = __builtin_amdgcn_mfma_f32_16x16x32_bf16(af[i], bfr[j], acc[i][j], 0, 0, 0);
        }

#pragma unroll
        for (int i = 0; i < 4; i++)
#pragma unroll
          for (int j = 0; j < 4; j++) {
            int gn = n0 + wn * 64 + j * 16 + r16;
            float bv = bih[gn];
#pragma unroll
            for (int r = 0; r < 4; r++) {
              int gm = m0 + wm * 64 + i * 16 + (kq << 2) + r;
              xpc_nxt[(size_t)gm * H3_ + gn] = f2b(acc[i][j][r] + bv);
            }
          }
        __syncthreads();
      }
    }

    // Phase 2: score tiles for chunk tc-1 (rows written by previous launch)
    if (t0 >= CHUNK) {
      const size_t crow = (size_t)(t0 - CHUNK) * B_;   // 8192 rows
#pragma unroll
      for (int q = 0; q < 2; q++) {
        int t  = p + q * 128;        // 0..255 = 64 row-blocks x 4 col-blocks
        int rb = t >> 2, cb = t & 3;
        score_tile(smem, enc_out, sw1, sb1, sw2, part,
                   crow + (size_t)rb * 128, cb * 128, tid);
      }
    }

    // Phase 3 (tc==7): convert decoder weights fp32 -> bf16
    if (dwih_f != nullptr) {
      const size_t N = (size_t)H3_ * H_;
      for (size_t i = (size_t)p * 256 + tid; i < N; i += 128 * 256) {
        dwih_b[i] = f2b(dwih_f[i]);
        dwhh_b[i] = f2b(dwhh_f[i]);
      }
    }
  }
}

// decoder GRUCell gates: gi,gh fp32; hs32 fp32 master, hs16 bf16 copy
__global__ void dec_gates(const float* __restrict__ gi, const float* __restrict__ gh,
                          float* __restrict__ hs32, bf16* __restrict__ hs16)
{
  int idx = blockIdx.x * blockDim.x + threadIdx.x;
  int b = idx >> 10, j = idx & (H_ - 1);
  const float* gir = gi + (size_t)b * H3_;
  const float* ghr = gh + (size_t)b * H3_;
  float r = sigm(gir[j] + ghr[j]);
  float z = sigm(gir[j + H_] + ghr[j + H_]);
  float n = tanhf(gir[j + 2 * H_] + r * ghr[j + 2 * H_]);
  float hnew = (1.f - z) * n + z * hs32[idx];
  hs32[idx] = hnew;
  hs16[idx] = f2b(hnew);
}

// per-b softmax over t (logit = sum of 4 part slots, in-kernel) then
// Rep[b] = sum_t w_t * enc_out[t,b,:]
__global__ void attention(const float* __restrict__ part, const bf16* __restrict__ enc_out,
                          float* __restrict__ rep, float* __restrict__ hs32,
                          bf16* __restrict__ hs16)
{
  int b = blockIdx.x, t = threadIdx.x;
  __shared__ float w[T_];
  __shared__ float red[T_];
  const float* pr = part + ((size_t)t * B_ + b) * 4;
  float lg = pr[0] + pr[1] + pr[2] + pr[3];
  red[t] = lg; __syncthreads();
  for (int s = 128; s > 0; s >>= 1) { if (t < s) red[t] = fmaxf(red[t], red[t + s]); __syncthreads(); }
  float mx = red[0]; __syncthreads();
  float e = __expf(lg - mx);
  w[t] = e; red[t] = e; __syncthreads();
  for (int s = 128; s > 0; s >>= 1) { if (t < s) red[t] += red[t + s]; __syncthreads(); }
  float inv = 1.f / red[0];
  float acc[4] = {0.f, 0.f, 0.f, 0.f};
  for (int tt = 0; tt < T_; tt++) {
    float wt = w[tt] * inv;
    const bf16* row = enc_out + ((size_t)tt * B_ + b) * H_;
#pragma unroll
    for (int i = 0; i < 4; i++) acc[i] += wt * b2f(row[t + i * 256]);
  }
#pragma unroll
  for (int i = 0; i < 4; i++) {
    int j = t + i * 256;
    rep [(size_t)b * H_ + j] = acc[i];
    hs32[(size_t)b * H_ + j] = acc[i];
    hs16[(size_t)b * H_ + j] = f2b(acc[i]);
  }
}

// pred[b][n] = dot(e1[b,:512], l2p_w2[n,:]) + b2[n]; write d_out and feed back ppad
__global__ void pred_k(const bf16* __restrict__ e1, const float* __restrict__ w2,
                       const float* __restrict__ b2, float* __restrict__ out,
                       bf16* __restrict__ ppad, int s)
{
  int b = blockIdx.x, t = threadIdx.x;
  __shared__ float ev[HID_];
  for (int k = t; k < HID_; k += 256) ev[k] = b2f(e1[(size_t)b * HID_ + k]);
  __syncthreads();
  if (t < D_) {
    float acc = b2[t];
    const float* wr = w2 + (size_t)t * HID_;
    for (int k = 0; k < HID_; k++) acc += ev[k] * wr[k];
    out[(size_t)b * (NPRED * D_) + s * D_ + t] = acc;
    ppad[b * DP_ + t] = f2b(acc);
  }
}

extern "C" void kernel_launch(void* const* d_in, const int* in_sizes, int n_in,
                              void* d_out, int out_size, void* d_ws, size_t ws_size,
                              hipStream_t stream)
{
  const float* x       = (const float*)d_in[0];
  const float* p2l_w1  = (const float*)d_in[2];
  const float* p2l_b1  = (const float*)d_in[3];
  const float* p2l_w2  = (const float*)d_in[4];
  const float* p2l_b2  = (const float*)d_in[5];
  const float* enc_wih = (const float*)d_in[6];
  const float* enc_whh = (const float*)d_in[7];
  const float* enc_bih = (const float*)d_in[8];
  const float* enc_bhh = (const float*)d_in[9];
  const float* dec_wih = (const float*)d_in[10];
  const float* dec_whh = (const float*)d_in[11];
  const float* dec_bih = (const float*)d_in[12];
  const float* dec_bhh = (const float*)d_in[13];
  const float* l2p_w1  = (const float*)d_in[14];
  const float* l2p_b1  = (const float*)d_in[15];
  const float* l2p_w2  = (const float*)d_in[16];
  const float* l2p_b2  = (const float*)d_in[17];
  const float* l2s_w1  = (const float*)d_in[18];
  const float* l2s_b1  = (const float*)d_in[19];
  const float* l2s_w2  = (const float*)d_in[20];
  const float* l2s_b2  = (const float*)d_in[21];
  (void)l2s_b2;  // scalar logit bias -- softmax-invariant, legally dropped

  float* out_preds = (float*)d_out;
  float* out_rep   = (float*)d_out + (size_t)B_ * NPRED * D_;

  // ---- workspace carve-up (256B aligned); ~167 MB total ----
  char* p = (char*)d_ws;
  auto alloc = [&](size_t bytes) -> char* {
    char* r = p; p += (bytes + 255) & ~(size_t)255; return r;
  };
  bf16* w_p2l1 = (bf16*)alloc((size_t)HID_ * DP_ * 2);
  bf16* w_p2l2 = (bf16*)alloc((size_t)H_ * HID_ * 2);
  bf16* w_ewih = (bf16*)alloc((size_t)H3_ * H_ * 2);
  bf16* w_ewhh = (bf16*)alloc((size_t)H3_ * H_ * 2);
  bf16* w_dwih = (bf16*)alloc((size_t)H3_ * H_ * 2);
  bf16* w_dwhh = (bf16*)alloc((size_t)H3_ * H_ * 2);
  bf16* w_l2p1 = (bf16*)alloc((size_t)HID_ * H_ * 2);
  bf16* w_l2s1 = (bf16*)alloc((size_t)HID_ * H_ * 2);
  bf16* latent = (bf16*)alloc((size_t)B_ * T_ * H_ * 2);     // t-major; = enc_out
  bf16* xpcA   = (bf16*)alloc((size_t)CHUNK * B_ * H3_ * 2); // 50.3 MB
  bf16* xpcB   = (bf16*)alloc((size_t)CHUNK * B_ * H3_ * 2); // 50.3 MB
  float* part_g= (float*)alloc((size_t)B_ * T_ * 4 * 4);     // 1 MB score partials
  float* h32  = (float*)alloc((size_t)B_ * H_ * 4);
  float* hs32 = (float*)alloc((size_t)B_ * H_ * 4);
  bf16*  hs16 = (bf16*) alloc((size_t)B_ * H_ * 2);
  bf16*  d1   = (bf16*) alloc((size_t)B_ * HID_ * 2);
  bf16*  inp  = (bf16*) alloc((size_t)B_ * H_ * 2);
  bf16*  e1   = (bf16*) alloc((size_t)B_ * HID_ * 2);
  bf16*  ppad = (bf16*) alloc((size_t)B_ * DP_ * 2);
  unsigned* bar = (unsigned*)alloc(2048);
  bf16*  enc_out = latent;

  // unions inside xpc buffers (phases never overlap):
  bf16* xb    = xpcB;                                        // [TB, DP] pre-encoder
  bf16* tmpc  = xpcB + (size_t)B_ * T_ * DP_;                // [RA, HID] (16.7MB ok)
  float* ghb  = (float*)(xpcA + (size_t)8 * 1024 * 1024);    // decoder (16MB in)
  float* gib  = ghb + (size_t)B_ * H3_;

  if ((size_t)(p - (char*)d_ws) > ws_size) return;

  const int TB = B_ * T_;  // 65536

  // ---- weight / input conversions to bf16 (decoder weights done in enc tc=7) ----
  auto cgrid = [](size_t n) { return dim3((unsigned)((n + 255) / 256)); };
  convert_pad<<<cgrid((size_t)TB * DP_),   256, 0, stream>>>(x,       xb,     TB,   D_,   DP_);
  convert_pad<<<cgrid((size_t)HID_ * DP_), 256, 0, stream>>>(p2l_w1,  w_p2l1, HID_, D_,   DP_);
  convert_pad<<<cgrid((size_t)H_ * HID_),  256, 0, stream>>>(p2l_w2,  w_p2l2, H_,   HID_, HID_);
  convert_pad<<<cgrid((size_t)H3_ * H_),   256, 0, stream>>>(enc_wih, w_ewih, H3_,  H_,   H_);
  convert_pad<<<cgrid((size_t)H3_ * H_),   256, 0, stream>>>(enc_whh, w_ewhh, H3_,  H_,   H_);
  convert_pad<<<cgrid((size_t)HID_ * H_),  256, 0, stream>>>(l2p_w1,  w_l2p1, HID_, H_,   H_);
  convert_pad<<<cgrid((size_t)HID_ * H_),  256, 0, stream>>>(l2s_w1,  w_l2s1, HID_, H_,   H_);

  // ---- par2lat(x) in 16384-row slabs (xb/tmpc in xpcB; consumed before producers) ----
  for (int rc = 0; rc < TB / RA; rc++) {
    { dim3 g(HID_ / 128, RA / 128);
      gemm_bt<128,128,64,64,EPI_BF16_RELU><<<g, 256, 0, stream>>>(
          xb + (size_t)rc * RA * DP_, w_p2l1, p2l_b1, tmpc, RA, HID_, DP_, 0); }
    { dim3 g(H_ / 128, RA / 128);
      gemm_bt<128,128,64,64,EPI_BF16_RELU_PERM><<<g, 256, 0, stream>>>(
          tmpc, w_p2l2, p2l_b2, latent, RA, H_, HID_, rc * RA); }
  }

  // ---- encoder: xp chunk 0 standalone, then fused launches ----
  (void)hipFuncSetAttribute((const void*)enc_fused,
                            hipFuncAttributeMaxDynamicSharedMemorySize, ENC_SMEM);
  enc_init<<<(B_ * H_) / 256, 256, 0, stream>>>(h32, bar);
  { dim3 g(H3_ / 128, (CHUNK * B_) / 128);
    gemm_bt<128,128,64,64,EPI_BF16><<<g, 256, 0, stream>>>(
        latent, w_ewih, enc_bih, xpcA, CHUNK * B_, H3_, H_, 0); }
  for (int tc = 0; tc < T_ / CHUNK; tc++) {
    bf16* cur = (tc & 1) ? xpcB : xpcA;
    bf16* nxt = (tc < 7) ? ((tc & 1) ? xpcA : xpcB) : nullptr;
    const bf16* latn = latent + (size_t)(tc + 1 < 8 ? tc + 1 : 0) * CHUNK * B_ * H_;
    const bool last = (tc == 7);
    enc_fused<<<dim3(256), dim3(256), ENC_SMEM, stream>>>(
        cur, w_ewhh, enc_bhh, enc_out, h32, bar, tc * CHUNK,
        latn, w_ewih, enc_bih, nxt,
        w_l2s1, l2s_b1, l2s_w2, part_g,
        last ? dec_wih : nullptr, last ? dec_whh : nullptr, w_dwih, w_dwhh);
  }

  // ---- attention: score for chunk 7 + softmax-pool (logits_red fused) ----
  score_gemm<<<dim3(4, 64), 256, 0, stream>>>(
      enc_out, w_l2s1, l2s_b1, l2s_w2, part_g, 7 * CHUNK * B_);
  attention<<<B_, 256, 0, stream>>>(part_g, enc_out, out_rep, hs32, hs16);

  // ---- decoder: weights already converted (enc tc=7); 10 autoregressive steps ----
  ppad_init<<<(B_ * DP_) / 256, 256, 0, stream>>>(x, ppad);
  for (int s = 0; s < NPRED; s++) {
    { dim3 g(HID_ / 128, B_ / 64);
      gemm_bt<64,128,32,64,EPI_BF16_RELU><<<g, 256, 0, stream>>>(ppad, w_p2l1, p2l_b1, d1, B_, HID_, DP_, 0); }
    { dim3 g(H_ / 128, B_ / 64);
      gemm_bt<64,128,32,64,EPI_BF16_RELU><<<g, 256, 0, stream>>>(d1, w_p2l2, p2l_b2, inp, B_, H_, HID_, 0); }
    { dim3 g(H3_ / 128, B_ / 64, 2);
      gemm_bt_dual<<<g, 256, 0, stream>>>(inp, w_dwih, dec_bih, gib,
                                          hs16, w_dwhh, dec_bhh, ghb, B_, H3_, H_); }
    dec_gates<<<(B_ * H_) / 256, 256, 0, stream>>>(gib, ghb, hs32, hs16);
    { dim3 g(HID_ / 128, B_ / 64);
      gemm_bt<64,128,32,64,EPI_BF16_RELU><<<g, 256, 0, stream>>>(hs16, w_l2p1, l2p_b1, e1, B_, HID_, H_, 0); }
    pred_k<<<B_, 256, 0, stream>>>(e1, l2p_w2, l2p_b2, out_preds, ppad, s);
  }
}

// Round 11
// 3205.351 us; speedup vs baseline: 1.0508x; 1.0508x over previous
//
#include <hip/hip_runtime.h>
#include <hip/hip_bf16.h>
#include <cstdint>
#include <cstddef>

// Model_69647189672235: GRU encoder-decoder w/ attention pooling.
// B=256 T=256 D=72 HID=512 H=1024, to_predict=10 (hardcoded; scalar input ignored).
// R13: fix R12's regression. R12 fused score tiles into EVERY launch's producers,
// but producers were already near-critical (~270us vs 276 recurrence) -> enc_fused
// became producer-bound at 300us (+200 total) > the ~155us tail saving. The only
//真 idle producers are tc=7's (no next chunk). Now: tc<7 producers = xp only
// (R11 workload); tc=7 producers = 12 score tiles each (chunks 0-5) + decoder
// weight converts; standalone score covers chunks 6-7 only (grid 4x128, ~35us).
// Keep RA=16384, dual decoder GEMM, logits_red fused into attention.
// R12 = 3368, R11 = 3242. Predicted ~3150; enc_fused tc<7 back to ~276us.

using bf16 = __hip_bfloat16;
typedef __attribute__((ext_vector_type(8))) short short8;
typedef __attribute__((ext_vector_type(4))) short s4_t;
typedef __attribute__((ext_vector_type(4))) float floatx4;

#define B_    256
#define T_    256
#define D_    72
#define DP_   96      // D padded to mult of 32 for BK=32
#define HID_  512
#define H_    1024
#define H3_   3072
#define NPRED 10
#define CHUNK 32      // encoder timesteps per persistent launch
#define RA    16384   // rows per slab in chunked par2lat GEMMs

__device__ __forceinline__ float b2f(bf16 v){ return __bfloat162float(v); }
__device__ __forceinline__ bf16  f2b(float v){ return __float2bfloat16(v); }

__device__ __forceinline__ void async_ld16(const bf16* g, bf16* l) {
  __builtin_amdgcn_global_load_lds(
      (const __attribute__((address_space(1))) unsigned int*)g,
      (__attribute__((address_space(3))) unsigned int*)l,
      16, 0, 0);
}

// Cached 16B load; asm keeps it below the poll and countable by vmcnt.
__device__ __forceinline__ short8 load16_cached(const bf16* p) {
  short8 r;
  asm volatile("global_load_dwordx4 %0, %1, off"
               : "=v"(r) : "v"(p) : "memory");
  return r;
}
// LLC write-through 8B store for cross-XCD visibility of h.
__device__ __forceinline__ void store8_llc(bf16* p, s4_t v) {
  asm volatile("global_store_dwordx2 %0, %1, off sc0 sc1"
               :: "v"(p), "v"(v) : "memory");
}

enum { EPI_F32 = 0, EPI_BF16 = 1, EPI_BF16_RELU = 2, EPI_BF16_RELU_PERM = 3 };

// C = epi(A @ B^T + bias). A:[M,K] bf16 row-major, B:[N,K] bf16 row-major.
template<int BM, int BN, int WM, int WN, int EPI>
__global__ __launch_bounds__(256, 2) void gemm_bt(
    const bf16* __restrict__ A, const bf16* __restrict__ B,
    const float* __restrict__ bias, void* __restrict__ Cout,
    int M, int N, int K, int row_off)
{
  constexpr int BK = 32;
  constexpr int NWN = BN / WN;
  constexpr int MT = WM / 16, NT = WN / 16;
  constexpr int ASEG = BM * 4;
  constexpr int TSEG = (BM + BN) * 4;
  static_assert((BM/WM)*(BN/WN) == 4, "4 waves");
  static_assert(TSEG % 256 == 0, "uniform staging");

  __shared__ __align__(16) bf16 smem[(BM + BN) * BK];
  bf16* As = smem;
  bf16* Bs = smem + BM * BK;

  const int tid  = threadIdx.x;
  const int lane = tid & 63;
  const int wave = tid >> 6;
  const int wm = wave / NWN, wn = wave % NWN;
  const int m0 = blockIdx.y * BM, n0 = blockIdx.x * BN;

  floatx4 acc[MT][NT];
#pragma unroll
  for (int i = 0; i < MT; i++)
#pragma unroll
    for (int j = 0; j < NT; j++)
      acc[i][j] = floatx4{0.f, 0.f, 0.f, 0.f};

  const int krow = (lane >> 4) << 3;
  const int r16  = lane & 15;

  for (int k0 = 0; k0 < K; k0 += BK) {
    __syncthreads();
#pragma unroll
    for (int it = 0; it < TSEG / 256; it++) {
      int s = tid + it * 256;
      const bf16* g;
      if (s < ASEG) {
        int row = s >> 2, kseg = s & 3;
        g = A + (size_t)(m0 + row) * K + k0 + kseg * 8;
      } else {
        int s2 = s - ASEG;
        int row = s2 >> 2, kseg = s2 & 3;
        g = B + (size_t)(n0 + row) * K + k0 + kseg * 8;
      }
      async_ld16(g, smem + (size_t)s * 8);
    }
    __syncthreads();
    short8 af[MT], bfr[NT];
#pragma unroll
    for (int i = 0; i < MT; i++)
      af[i] = *(const short8*)(As + (wm * WM + i * 16 + r16) * BK + krow);
#pragma unroll
    for (int j = 0; j < NT; j++)
      bfr[j] = *(const short8*)(Bs + (wn * WN + j * 16 + r16) * BK + krow);
#pragma unroll
    for (int i = 0; i < MT; i++)
#pragma unroll
      for (int j = 0; j < NT; j++)
        acc[i][j] = __builtin_amdgcn_mfma_f32_16x16x32_bf16(af[i], bfr[j], acc[i][j], 0, 0, 0);
  }

#pragma unroll
  for (int i = 0; i < MT; i++) {
#pragma unroll
    for (int j = 0; j < NT; j++) {
      int gn = n0 + wn * WN + j * 16 + r16;
      float bv = bias ? bias[gn] : 0.f;
#pragma unroll
      for (int r = 0; r < 4; r++) {
        int gm = m0 + wm * WM + i * 16 + ((lane >> 4) << 2) + r;
        float v = acc[i][j][r] + bv;
        if (EPI == EPI_BF16_RELU || EPI == EPI_BF16_RELU_PERM) v = fmaxf(v, 0.f);
        size_t orow;
        if (EPI == EPI_BF16_RELU_PERM) {
          int g = row_off + gm;
          orow = (size_t)(g & 255) * 256 + (size_t)(g >> 8);
        } else {
          orow = (size_t)gm;
        }
        if (EPI == EPI_F32) ((float*)Cout)[orow * (size_t)N + gn] = v;
        else                ((bf16*) Cout)[orow * (size_t)N + gn] = f2b(v);
      }
    }
  }
}

// Dual GEMM (two independent 64x128-tile EPI_F32 GEMMs selected by blockIdx.z).
__global__ __launch_bounds__(256, 2) void gemm_bt_dual(
    const bf16* __restrict__ A0, const bf16* __restrict__ B0,
    const float* __restrict__ bias0, float* __restrict__ C0,
    const bf16* __restrict__ A1, const bf16* __restrict__ B1,
    const float* __restrict__ bias1, float* __restrict__ C1,
    int M, int N, int K)
{
  constexpr int BM = 64, BN = 128, BK = 32;
  constexpr int ASEG = BM * 4, TSEG = (BM + BN) * 4;
  const bf16* A = blockIdx.z ? A1 : A0;
  const bf16* B = blockIdx.z ? B1 : B0;
  const float* bias = blockIdx.z ? bias1 : bias0;
  float* Cout = blockIdx.z ? C1 : C0;

  __shared__ __align__(16) bf16 smem[(BM + BN) * BK];
  bf16* As = smem;
  bf16* Bs = smem + BM * BK;

  const int tid  = threadIdx.x;
  const int lane = tid & 63;
  const int wave = tid >> 6;
  const int wm = wave >> 1, wn = wave & 1;   // WM=32, WN=64 -> MT=2, NT=4
  const int m0 = blockIdx.y * BM, n0 = blockIdx.x * BN;

  floatx4 acc[2][4];
#pragma unroll
  for (int i = 0; i < 2; i++)
#pragma unroll
    for (int j = 0; j < 4; j++)
      acc[i][j] = floatx4{0.f, 0.f, 0.f, 0.f};

  const int krow = (lane >> 4) << 3;
  const int r16  = lane & 15;

  for (int k0 = 0; k0 < K; k0 += BK) {
    __syncthreads();
#pragma unroll
    for (int it = 0; it < TSEG / 256; it++) {
      int s = tid + it * 256;
      const bf16* g;
      if (s < ASEG) {
        int row = s >> 2, kseg = s & 3;
        g = A + (size_t)(m0 + row) * K + k0 + kseg * 8;
      } else {
        int s2 = s - ASEG;
        int row = s2 >> 2, kseg = s2 & 3;
        g = B + (size_t)(n0 + row) * K + k0 + kseg * 8;
      }
      async_ld16(g, smem + (size_t)s * 8);
    }
    __syncthreads();
    short8 af[2], bfr[4];
#pragma unroll
    for (int i = 0; i < 2; i++)
      af[i] = *(const short8*)(As + (wm * 32 + i * 16 + r16) * BK + krow);
#pragma unroll
    for (int j = 0; j < 4; j++)
      bfr[j] = *(const short8*)(Bs + (wn * 64 + j * 16 + r16) * BK + krow);
#pragma unroll
    for (int i = 0; i < 2; i++)
#pragma unroll
      for (int j = 0; j < 4; j++)
        acc[i][j] = __builtin_amdgcn_mfma_f32_16x16x32_bf16(af[i], bfr[j], acc[i][j], 0, 0, 0);
  }

#pragma unroll
  for (int i = 0; i < 2; i++)
#pragma unroll
    for (int j = 0; j < 4; j++) {
      int gn = n0 + wn * 64 + j * 16 + r16;
      float bv = bias[gn];
#pragma unroll
      for (int r = 0; r < 4; r++) {
        int gm = m0 + wm * 32 + i * 16 + ((lane >> 4) << 2) + r;
        Cout[(size_t)gm * N + gn] = acc[i][j][r] + bv;
      }
    }
}

// One 128x128 score tile: part[m0+row][n0>>7] = sum_{gn in block}
//   relu(enc_out[row,:] . l2s_w1[gn,:] + b1[gn]) * w2[gn]
// Deterministic (unique-writer partials). smem needs 16KB GEMM + 16.9KB pl.
__device__ __forceinline__ void score_tile(
    char* sm, const bf16* __restrict__ A, const bf16* __restrict__ Bw,
    const float* __restrict__ b1, const float* __restrict__ w2,
    float* __restrict__ part, size_t m0, int n0, int tid)
{
  constexpr int BK = 32;
  bf16* As = (bf16*)sm;
  bf16* Bs = As + 128 * BK;
  float* pl = (float*)(sm + 16384);   // [128][33]

  const int lane = tid & 63;
  const int wave = tid >> 6;
  const int wm = wave >> 1, wn = wave & 1;   // 2x2 waves, WM=WN=64
  const int krow = (lane >> 4) << 3;
  const int r16  = lane & 15;
  const int kq   = lane >> 4;

  floatx4 acc[4][4];
#pragma unroll
  for (int i = 0; i < 4; i++)
#pragma unroll
    for (int j = 0; j < 4; j++)
      acc[i][j] = floatx4{0.f, 0.f, 0.f, 0.f};

  for (int k0 = 0; k0 < H_; k0 += BK) {
    __syncthreads();
#pragma unroll
    for (int it = 0; it < 4; it++) {
      int s = tid + it * 256;
      const bf16* g;
      if (s < 512) {
        int row = s >> 2, kseg = s & 3;
        g = A + (m0 + row) * H_ + k0 + kseg * 8;
      } else {
        int s2 = s - 512;
        int row = s2 >> 2, kseg = s2 & 3;
        g = Bw + (size_t)(n0 + row) * H_ + k0 + kseg * 8;
      }
      async_ld16(g, As + (size_t)s * 8);
    }
    __syncthreads();
    short8 af[4], bfr[4];
#pragma unroll
    for (int i = 0; i < 4; i++)
      af[i] = *(const short8*)(As + (wm * 64 + i * 16 + r16) * BK + krow);
#pragma unroll
    for (int j = 0; j < 4; j++)
      bfr[j] = *(const short8*)(Bs + (wn * 64 + j * 16 + r16) * BK + krow);
#pragma unroll
    for (int i = 0; i < 4; i++)
#pragma unroll
      for (int j = 0; j < 4; j++)
        acc[i][j] = __builtin_amdgcn_mfma_f32_16x16x32_bf16(af[i], bfr[j], acc[i][j], 0, 0, 0);
  }

#pragma unroll
  for (int i = 0; i < 4; i++) {
#pragma unroll
    for (int r = 0; r < 4; r++) {
      int row = wm * 64 + i * 16 + kq * 4 + r;
      float s = 0.f;
#pragma unroll
      for (int j = 0; j < 4; j++) {
        int gn = n0 + wn * 64 + j * 16 + r16;
        s += fmaxf(acc[i][j][r] + b1[gn], 0.f) * w2[gn];
      }
      pl[row * 33 + wn * 16 + r16] = s;
    }
  }
  __syncthreads();
  if (tid < 128) {
    float t = 0.f;
#pragma unroll
    for (int c = 0; c < 32; c++) t += pl[tid * 33 + c];
    part[(m0 + tid) * 4 + (n0 >> 7)] = t;
  }
  __syncthreads();
}

// standalone score (chunks 6-7): grid (4, 128)
__global__ __launch_bounds__(256, 2) void score_gemm(
    const bf16* __restrict__ A, const bf16* __restrict__ Bw,
    const float* __restrict__ b1, const float* __restrict__ w2,
    float* __restrict__ part, int m_off)
{
  __shared__ __align__(16) char sbuf[33536];
  score_tile(sbuf, A, Bw, b1, w2, part,
             (size_t)m_off + (size_t)blockIdx.y * 128, blockIdx.x * 128,
             threadIdx.x);
}

// fp32 -> bf16 with K padding (kout >= kin, pad zeros)
__global__ void convert_pad(const float* __restrict__ in, bf16* __restrict__ out,
                            int rows, int kin, int kout)
{
  size_t idx = (size_t)blockIdx.x * blockDim.x + threadIdx.x;
  if (idx >= (size_t)rows * kout) return;
  int r = idx / kout, c = idx % kout;
  out[idx] = (c < kin) ? f2b(in[(size_t)r * kin + c]) : f2b(0.f);
}

// zero h32 master + flags
__global__ void enc_init(float* __restrict__ h32, unsigned* __restrict__ bar)
{
  int idx = blockIdx.x * blockDim.x + threadIdx.x;
  h32[idx] = 0.f;
  if (idx < 512) bar[idx] = 0u;
}

// ppad[b][0:72] = bf16(x[b, T-1, :]), rest 0
__global__ void ppad_init(const float* __restrict__ x, bf16* __restrict__ ppad)
{
  int idx = blockIdx.x * blockDim.x + threadIdx.x;
  int b = idx / DP_, c = idx % DP_;
  float v = (c < D_) ? x[((size_t)b * T_ + (T_ - 1)) * D_ + c] : 0.f;
  ppad[idx] = f2b(v);
}

__device__ __forceinline__ float sigm(float v){ return 1.f / (1.f + __expf(-v)); }

// ---------------- fused encoder: recurrence + producer ----------------
// wgs 0..127 recurrence: unchanged (proven): 32 h-cols/wg (16 LDS + 16 reg
// weights), k-split waves, 2-pass P reduce, 8-flag quarter poll, sc0|sc1 h
// stores, cached h loads.
// wgs 128..255 producer: tc<7 -> 12 xp tiles for chunk tc+1 (R11 workload,
// near-critical -- nothing added). tc==7 (xpc_nxt==null, truly idle) ->
// 12 score tiles each (chunks 0-5) + decoder weight converts.
#define ENC_SMEM (98304 + 4*64*52*4)   // 96KB weights + 52-padded P = 151552 B
static_assert(ENC_SMEM <= 160*1024, "LDS");
static_assert(ENC_SMEM >= 33536, "producer score smem fits");

__global__ __launch_bounds__(256, 1) void enc_fused(
    const bf16* __restrict__ xpc_cur,  // [CHUNK*B, 3H] this chunk's gi (bih included)
    const bf16* __restrict__ whh,      // [3H, H]
    const float* __restrict__ bhh,     // [3H]
    bf16* __restrict__ enc_out,        // [T*B, H] t-major h16 history
    float* __restrict__ h32g,          // [B, H] fp32 master (chunk handoff)
    unsigned* __restrict__ bar,        // flags[4][32]
    int t0,
    const bf16* __restrict__ lat_nxt,  // latent slab for chunk tc+1
    const bf16* __restrict__ wih,      // [3H, H]
    const float* __restrict__ bih,     // [3H]
    bf16* __restrict__ xpc_nxt,        // [CHUNK*B, 3H] or null (tc==7)
    const bf16* __restrict__ sw1,      // l2s_w1 bf16 [512,1024]
    const float* __restrict__ sb1,     // l2s_b1
    const float* __restrict__ sw2,     // l2s_w2
    float* __restrict__ part,          // [T*B, 4]
    const float* __restrict__ dwih_f,  // dec_wih fp32 (tc==7 else null)
    const float* __restrict__ dwhh_f,
    bf16* __restrict__ dwih_b,
    bf16* __restrict__ dwhh_b)
{
  extern __shared__ char smem[];
  const int tid  = threadIdx.x;
  const int lane = tid & 63;
  const int wave = tid >> 6;
  const int wg   = blockIdx.x;
  const int r16  = lane & 15;
  const int kq   = lane >> 4;

  if (wg < 128) {
    // ================= recurrence (unchanged from R11) =================
    float* P = (float*)(smem + 98304);
    constexpr int PS = 52;

    const int rgrp = wg >> 5;
    const int rowb = rgrp * 64;
    const int j0   = (wg & 31) * 32;
    const int kb0  = wave * 256;

    unsigned* flagp  = bar + rgrp * 32 + wave * 8 + (lane & 7);
    unsigned* myflag = bar + rgrp * 32 + (wg & 31);

    for (int ci = tid; ci < 48 * 128; ci += 256) {
      int wrow = ci >> 7, kslot = ci & 127;
      int g = wrow >> 4, jj = wrow & 15;
      short8 v = *(const short8*)(whh + ((size_t)(g * H_ + j0 + jj)) * H_ + kslot * 8);
      *(short8*)(smem + kslot * 768 + wrow * 16) = v;
    }
    short8 rw[8][3];
#pragma unroll
    for (int it = 0; it < 8; it++)
#pragma unroll
      for (int g = 0; g < 3; g++)
        rw[it][g] = *(const short8*)(whh + ((size_t)(g * H_ + j0 + 16 + r16)) * H_
                                     + kb0 + it * 32 + kq * 8);

    const int row_loc = tid >> 2;
    const int cq      = tid & 3;
    const int b       = rowb + row_loc;
    const int jb0     = j0 + cq * 4;
    const int jb1     = j0 + 16 + cq * 4;

    floatx4 h32r0 = *(const floatx4*)(h32g + (size_t)b * H_ + jb0);
    floatx4 h32r1 = *(const floatx4*)(h32g + (size_t)b * H_ + jb1);
    const floatx4 bhr0 = *(const floatx4*)(bhh + jb0);
    const floatx4 bhz0 = *(const floatx4*)(bhh + H_ + jb0);
    const floatx4 bhn0 = *(const floatx4*)(bhh + 2 * H_ + jb0);
    const floatx4 bhr1 = *(const floatx4*)(bhh + jb1);
    const floatx4 bhz1 = *(const floatx4*)(bhh + H_ + jb1);
    const floatx4 bhn1 = *(const floatx4*)(bhh + 2 * H_ + jb1);

    __syncthreads();

#define ISSUE(IT)                                                              \
    {                                                                          \
      _Pragma("unroll")                                                        \
      for (int rf = 0; rf < 4; rf++)                                           \
        a[(IT) & 3][rf] = load16_cached(hsrc + (size_t)(rowb + rf * 16 + r16) * H_ \
                                        + kb0 + (IT) * 32 + kq * 8);           \
    }
#define GRP(IT, WC)                                                            \
    do {                                                                       \
      const char* bb = smem + (wave * 32 + (IT) * 4 + kq) * 768 + r16 * 16;    \
      short8 bw0 = *(const short8*)(bb);                                       \
      short8 bw1 = *(const short8*)(bb + 256);                                 \
      short8 bw2 = *(const short8*)(bb + 512);                                 \
      asm volatile("s_waitcnt vmcnt(" #WC ")" ::: "memory");                   \
      __builtin_amdgcn_sched_barrier(0);                                       \
      _Pragma("unroll")                                                        \
      for (int rf = 0; rf < 4; rf++) {                                         \
        accA[rf][0] = __builtin_amdgcn_mfma_f32_16x16x32_bf16(a[(IT)&3][rf], bw0, accA[rf][0], 0, 0, 0); \
        accA[rf][1] = __builtin_amdgcn_mfma_f32_16x16x32_bf16(a[(IT)&3][rf], bw1, accA[rf][1], 0, 0, 0); \
        accA[rf][2] = __builtin_amdgcn_mfma_f32_16x16x32_bf16(a[(IT)&3][rf], bw2, accA[rf][2], 0, 0, 0); \
        accB[rf][0] = __builtin_amdgcn_mfma_f32_16x16x32_bf16(a[(IT)&3][rf], rw[IT][0], accB[rf][0], 0, 0, 0); \
        accB[rf][1] = __builtin_amdgcn_mfma_f32_16x16x32_bf16(a[(IT)&3][rf], rw[IT][1], accB[rf][1], 0, 0, 0); \
        accB[rf][2] = __builtin_amdgcn_mfma_f32_16x16x32_bf16(a[(IT)&3][rf], rw[IT][2], accB[rf][2], 0, 0, 0); \
      }                                                                        \
      if ((IT) + 4 < 8) ISSUE((IT) + 4)                                        \
    } while (0)

    for (int ts = 0; ts < CHUNK; ts++) {
      const int tg = t0 + ts;

      const bf16* gi = xpc_cur + ((size_t)ts * B_ + b) * H3_;
      s4_t vr0 = *(const s4_t*)(gi + jb0);
      s4_t vz0 = *(const s4_t*)(gi + H_ + jb0);
      s4_t vn0 = *(const s4_t*)(gi + 2 * H_ + jb0);
      s4_t vr1 = *(const s4_t*)(gi + jb1);
      s4_t vz1 = *(const s4_t*)(gi + H_ + jb1);
      s4_t vn1 = *(const s4_t*)(gi + 2 * H_ + jb1);

      floatx4 accA[4][3], accB[4][3];
#pragma unroll
      for (int rf = 0; rf < 4; rf++)
#pragma unroll
        for (int g = 0; g < 3; g++) {
          accA[rf][g] = floatx4{0.f, 0.f, 0.f, 0.f};
          accB[rf][g] = floatx4{0.f, 0.f, 0.f, 0.f};
        }

      if (tg > 0) {
        const unsigned tgt = (unsigned)tg;
        while (1) {
          unsigned f;
          asm volatile("global_load_dword %0, %1, off sc0 sc1"
                       : "=v"(f) : "v"(flagp) : "memory");
          asm volatile("s_waitcnt vmcnt(0)" ::: "memory");
          if (__all((int)(f >= tgt))) break;
          __builtin_amdgcn_s_sleep(2);
        }
        const bf16* hsrc = enc_out + (size_t)(tg - 1) * B_ * H_;
        short8 a[4][4];
        ISSUE(0) ISSUE(1) ISSUE(2) ISSUE(3)
        GRP(0, 12); GRP(1, 12); GRP(2, 12); GRP(3, 12);
        GRP(4, 12); GRP(5,  8); GRP(6,  4); GRP(7,  0);
      }

      // pass 0: cols j0..j0+16
#pragma unroll
      for (int rf = 0; rf < 4; rf++)
#pragma unroll
        for (int g = 0; g < 3; g++)
#pragma unroll
          for (int rr = 0; rr < 4; rr++)
            P[(wave * 64 + rf * 16 + kq * 4 + rr) * PS + g * 16 + r16] = accA[rf][g][rr];
      __syncthreads();
      {
        const float* Pr = P + row_loc * PS + cq * 4;
        floatx4 sr4 = floatx4{0.f,0.f,0.f,0.f};
        floatx4 sz4 = floatx4{0.f,0.f,0.f,0.f};
        floatx4 sn4 = floatx4{0.f,0.f,0.f,0.f};
#pragma unroll
        for (int w = 0; w < 4; w++) {
          const float* pp = Pr + w * 64 * PS;
          sr4 += *(const floatx4*)(pp);
          sz4 += *(const floatx4*)(pp + 16);
          sn4 += *(const floatx4*)(pp + 32);
        }
        s4_t outv;
#pragma unroll
        for (int cc = 0; cc < 4; cc++) {
          float xr = __uint_as_float(((unsigned)(unsigned short)vr0[cc]) << 16);
          float xz = __uint_as_float(((unsigned)(unsigned short)vz0[cc]) << 16);
          float xn = __uint_as_float(((unsigned)(unsigned short)vn0[cc]) << 16);
          float rg = sigm(xr + sr4[cc] + bhr0[cc]);
          float zg = sigm(xz + sz4[cc] + bhz0[cc]);
          float ng = tanhf(xn + rg * (sn4[cc] + bhn0[cc]));
          float hnew = (1.f - zg) * ng + zg * h32r0[cc];
          h32r0[cc] = hnew;
          outv[cc] = (short)__builtin_bit_cast(unsigned short, f2b(hnew));
        }
        store8_llc(enc_out + ((size_t)tg * B_ + b) * H_ + jb0, outv);
      }
      __syncthreads();

      // pass 1: cols j0+16..j0+32
#pragma unroll
      for (int rf = 0; rf < 4; rf++)
#pragma unroll
        for (int g = 0; g < 3; g++)
#pragma unroll
          for (int rr = 0; rr < 4; rr++)
            P[(wave * 64 + rf * 16 + kq * 4 + rr) * PS + g * 16 + r16] = accB[rf][g][rr];
      __syncthreads();
      {
        const float* Pr = P + row_loc * PS + cq * 4;
        floatx4 sr4 = floatx4{0.f,0.f,0.f,0.f};
        floatx4 sz4 = floatx4{0.f,0.f,0.f,0.f};
        floatx4 sn4 = floatx4{0.f,0.f,0.f,0.f};
#pragma unroll
        for (int w = 0; w < 4; w++) {
          const float* pp = Pr + w * 64 * PS;
          sr4 += *(const floatx4*)(pp);
          sz4 += *(const floatx4*)(pp + 16);
          sn4 += *(const floatx4*)(pp + 32);
        }
        s4_t outv;
#pragma unroll
        for (int cc = 0; cc < 4; cc++) {
          float xr = __uint_as_float(((unsigned)(unsigned short)vr1[cc]) << 16);
          float xz = __uint_as_float(((unsigned)(unsigned short)vz1[cc]) << 16);
          float xn = __uint_as_float(((unsigned)(unsigned short)vn1[cc]) << 16);
          float rg = sigm(xr + sr4[cc] + bhr1[cc]);
          float zg = sigm(xz + sz4[cc] + bhz1[cc]);
          float ng = tanhf(xn + rg * (sn4[cc] + bhn1[cc]));
          float hnew = (1.f - zg) * ng + zg * h32r1[cc];
          h32r1[cc] = hnew;
          outv[cc] = (short)__builtin_bit_cast(unsigned short, f2b(hnew));
        }
        store8_llc(enc_out + ((size_t)tg * B_ + b) * H_ + jb1, outv);
      }

      asm volatile("s_waitcnt vmcnt(0)" ::: "memory");
      __syncthreads();
      if (tid == 0) {
        unsigned v = (unsigned)(tg + 1);
        asm volatile("global_store_dword %0, %1, off sc0 sc1"
                     :: "v"(myflag), "v"(v) : "memory");
      }
    }
#undef GRP
#undef ISSUE

    *(floatx4*)(h32g + (size_t)b * H_ + jb0) = h32r0;
    *(floatx4*)(h32g + (size_t)b * H_ + jb1) = h32r1;

  } else {
    // ================= producer =================
    const int p = wg - 128;

    if (xpc_nxt != nullptr) {
      // tc < 7: xp tiles for chunk tc+1 (R11 workload, unchanged)
      const int wm = wave >> 1, wn = wave & 1;
      bf16* As = (bf16*)smem;
      bf16* Bs = As + 128 * 32;
      const int krow = kq << 3;

      for (int tile = 0; tile < 12; tile++) {
        const int t  = p + tile * 128;           // 64 x 24 tiles of 128^2
        const int m0 = (t / 24) * 128;
        const int n0 = (t % 24) * 128;

        floatx4 acc[4][4];
#pragma unroll
        for (int i = 0; i < 4; i++)
#pragma unroll
          for (int j = 0; j < 4; j++)
            acc[i][j] = floatx4{0.f, 0.f, 0.f, 0.f};

        for (int k0 = 0; k0 < H_; k0 += 32) {
          __syncthreads();
#pragma unroll
          for (int it = 0; it < 4; it++) {
            int s = tid + it * 256;
            const bf16* g;
            if (s < 512) {
              int row = s >> 2, kseg = s & 3;
              g = lat_nxt + (size_t)(m0 + row) * H_ + k0 + kseg * 8;
            } else {
              int s2 = s - 512;
              int row = s2 >> 2, kseg = s2 & 3;
              g = wih + (size_t)(n0 + row) * H_ + k0 + kseg * 8;
            }
            async_ld16(g, (bf16*)smem + (size_t)s * 8);
          }
          __syncthreads();
          short8 af[4], bfr[4];
#pragma unroll
          for (int i = 0; i < 4; i++)
            af[i] = *(const short8*)(As + (wm * 64 + i * 16 + r16) * 32 + krow);
#pragma unroll
          for (int j = 0; j < 4; j++)
            bfr[j] = *(const short8*)(Bs + (wn * 64 + j * 16 + r16) * 32 + krow);
#pragma unroll
          for (int i = 0; i < 4; i++)
#pragma unroll
            for (int j = 0; j < 4; j++)
              acc[i][j] = __builtin_amdgcn_mfma_f32_16x16x32_bf16(af[i], bfr[j], acc[i][j], 0, 0, 0);
        }

#pragma unroll
        for (int i = 0; i < 4; i++)
#pragma unroll
          for (int j = 0; j < 4; j++) {
            int gn = n0 + wn * 64 + j * 16 + r16;
            float bv = bih[gn];
#pragma unroll
            for (int r = 0; r < 4; r++) {
              int gm = m0 + wm * 64 + i * 16 + (kq << 2) + r;
              xpc_nxt[(size_t)gm * H3_ + gn] = f2b(acc[i][j][r] + bv);
            }
          }
        __syncthreads();
      }
    } else {
      // tc == 7: producers are otherwise idle. Score tiles for chunks 0-5
      // (rows 0..49151 = 384 row-blocks x 4 col-blocks = 1536 tiles, 12/wg),
      // then decoder weight converts.
      for (int q = 0; q < 12; q++) {
        int t  = p + q * 128;
        int rb = t >> 2, cb = t & 3;
        score_tile(smem, enc_out, sw1, sb1, sw2, part,
                   (size_t)rb * 128, cb * 128, tid);
      }
      const size_t N = (size_t)H3_ * H_;
      for (size_t i = (size_t)p * 256 + tid; i < N; i += 128 * 256) {
        dwih_b[i] = f2b(dwih_f[i]);
        dwhh_b[i] = f2b(dwhh_f[i]);
      }
    }
  }
}

// decoder GRUCell gates: gi,gh fp32; hs32 fp32 master, hs16 bf16 copy
__global__ void dec_gates(const float* __restrict__ gi, const float* __restrict__ gh,
                          float* __restrict__ hs32, bf16* __restrict__ hs16)
{
  int idx = blockIdx.x * blockDim.x + threadIdx.x;
  int b = idx >> 10, j = idx & (H_ - 1);
  const float* gir = gi + (size_t)b * H3_;
  const float* ghr = gh + (size_t)b * H3_;
  float r = sigm(gir[j] + ghr[j]);
  float z = sigm(gir[j + H_] + ghr[j + H_]);
  float n = tanhf(gir[j + 2 * H_] + r * ghr[j + 2 * H_]);
  float hnew = (1.f - z) * n + z * hs32[idx];
  hs32[idx] = hnew;
  hs16[idx] = f2b(hnew);
}

// per-b softmax over t (logit = sum of 4 part slots, in-kernel) then
// Rep[b] = sum_t w_t * enc_out[t,b,:]
__global__ void attention(const float* __restrict__ part, const bf16* __restrict__ enc_out,
                          float* __restrict__ rep, float* __restrict__ hs32,
                          bf16* __restrict__ hs16)
{
  int b = blockIdx.x, t = threadIdx.x;
  __shared__ float w[T_];
  __shared__ float red[T_];
  const float* pr = part + ((size_t)t * B_ + b) * 4;
  float lg = pr[0] + pr[1] + pr[2] + pr[3];
  red[t] = lg; __syncthreads();
  for (int s = 128; s > 0; s >>= 1) { if (t < s) red[t] = fmaxf(red[t], red[t + s]); __syncthreads(); }
  float mx = red[0]; __syncthreads();
  float e = __expf(lg - mx);
  w[t] = e; red[t] = e; __syncthreads();
  for (int s = 128; s > 0; s >>= 1) { if (t < s) red[t] += red[t + s]; __syncthreads(); }
  float inv = 1.f / red[0];
  float acc[4] = {0.f, 0.f, 0.f, 0.f};
  for (int tt = 0; tt < T_; tt++) {
    float wt = w[tt] * inv;
    const bf16* row = enc_out + ((size_t)tt * B_ + b) * H_;
#pragma unroll
    for (int i = 0; i < 4; i++) acc[i] += wt * b2f(row[t + i * 256]);
  }
#pragma unroll
  for (int i = 0; i < 4; i++) {
    int j = t + i * 256;
    rep [(size_t)b * H_ + j] = acc[i];
    hs32[(size_t)b * H_ + j] = acc[i];
    hs16[(size_t)b * H_ + j] = f2b(acc[i]);
  }
}

// pred[b][n] = dot(e1[b,:512], l2p_w2[n,:]) + b2[n]; write d_out and feed back ppad
__global__ void pred_k(const bf16* __restrict__ e1, const float* __restrict__ w2,
                       const float* __restrict__ b2, float* __restrict__ out,
                       bf16* __restrict__ ppad, int s)
{
  int b = blockIdx.x, t = threadIdx.x;
  __shared__ float ev[HID_];
  for (int k = t; k < HID_; k += 256) ev[k] = b2f(e1[(size_t)b * HID_ + k]);
  __syncthreads();
  if (t < D_) {
    float acc = b2[t];
    const float* wr = w2 + (size_t)t * HID_;
    for (int k = 0; k < HID_; k++) acc += ev[k] * wr[k];
    out[(size_t)b * (NPRED * D_) + s * D_ + t] = acc;
    ppad[b * DP_ + t] = f2b(acc);
  }
}

extern "C" void kernel_launch(void* const* d_in, const int* in_sizes, int n_in,
                              void* d_out, int out_size, void* d_ws, size_t ws_size,
                              hipStream_t stream)
{
  const float* x       = (const float*)d_in[0];
  const float* p2l_w1  = (const float*)d_in[2];
  const float* p2l_b1  = (const float*)d_in[3];
  const float* p2l_w2  = (const float*)d_in[4];
  const float* p2l_b2  = (const float*)d_in[5];
  const float* enc_wih = (const float*)d_in[6];
  const float* enc_whh = (const float*)d_in[7];
  const float* enc_bih = (const float*)d_in[8];
  const float* enc_bhh = (const float*)d_in[9];
  const float* dec_wih = (const float*)d_in[10];
  const float* dec_whh = (const float*)d_in[11];
  const float* dec_bih = (const float*)d_in[12];
  const float* dec_bhh = (const float*)d_in[13];
  const float* l2p_w1  = (const float*)d_in[14];
  const float* l2p_b1  = (const float*)d_in[15];
  const float* l2p_w2  = (const float*)d_in[16];
  const float* l2p_b2  = (const float*)d_in[17];
  const float* l2s_w1  = (const float*)d_in[18];
  const float* l2s_b1  = (const float*)d_in[19];
  const float* l2s_w2  = (const float*)d_in[20];
  const float* l2s_b2  = (const float*)d_in[21];
  (void)l2s_b2;  // scalar logit bias -- softmax-invariant, legally dropped

  float* out_preds = (float*)d_out;
  float* out_rep   = (float*)d_out + (size_t)B_ * NPRED * D_;

  // ---- workspace carve-up (256B aligned); ~167 MB total ----
  char* p = (char*)d_ws;
  auto alloc = [&](size_t bytes) -> char* {
    char* r = p; p += (bytes + 255) & ~(size_t)255; return r;
  };
  bf16* w_p2l1 = (bf16*)alloc((size_t)HID_ * DP_ * 2);
  bf16* w_p2l2 = (bf16*)alloc((size_t)H_ * HID_ * 2);
  bf16* w_ewih = (bf16*)alloc((size_t)H3_ * H_ * 2);
  bf16* w_ewhh = (bf16*)alloc((size_t)H3_ * H_ * 2);
  bf16* w_dwih = (bf16*)alloc((size_t)H3_ * H_ * 2);
  bf16* w_dwhh = (bf16*)alloc((size_t)H3_ * H_ * 2);
  bf16* w_l2p1 = (bf16*)alloc((size_t)HID_ * H_ * 2);
  bf16* w_l2s1 = (bf16*)alloc((size_t)HID_ * H_ * 2);
  bf16* latent = (bf16*)alloc((size_t)B_ * T_ * H_ * 2);     // t-major; = enc_out
  bf16* xpcA   = (bf16*)alloc((size_t)CHUNK * B_ * H3_ * 2); // 50.3 MB
  bf16* xpcB   = (bf16*)alloc((size_t)CHUNK * B_ * H3_ * 2); // 50.3 MB
  float* part_g= (float*)alloc((size_t)B_ * T_ * 4 * 4);     // 1 MB score partials
  float* h32  = (float*)alloc((size_t)B_ * H_ * 4);
  float* hs32 = (float*)alloc((size_t)B_ * H_ * 4);
  bf16*  hs16 = (bf16*) alloc((size_t)B_ * H_ * 2);
  bf16*  d1   = (bf16*) alloc((size_t)B_ * HID_ * 2);
  bf16*  inp  = (bf16*) alloc((size_t)B_ * H_ * 2);
  bf16*  e1   = (bf16*) alloc((size_t)B_ * HID_ * 2);
  bf16*  ppad = (bf16*) alloc((size_t)B_ * DP_ * 2);
  unsigned* bar = (unsigned*)alloc(2048);
  bf16*  enc_out = latent;

  // unions inside xpc buffers (phases never overlap):
  bf16* xb    = xpcB;                                        // [TB, DP] pre-encoder
  bf16* tmpc  = xpcB + (size_t)B_ * T_ * DP_;                // [RA, HID] (16.7MB ok)
  float* ghb  = (float*)(xpcA + (size_t)8 * 1024 * 1024);    // decoder (16MB in)
  float* gib  = ghb + (size_t)B_ * H3_;

  if ((size_t)(p - (char*)d_ws) > ws_size) return;

  const int TB = B_ * T_;  // 65536

  // ---- weight / input conversions to bf16 (decoder weights done in enc tc=7) ----
  auto cgrid = [](size_t n) { return dim3((unsigned)((n + 255) / 256)); };
  convert_pad<<<cgrid((size_t)TB * DP_),   256, 0, stream>>>(x,       xb,     TB,   D_,   DP_);
  convert_pad<<<cgrid((size_t)HID_ * DP_), 256, 0, stream>>>(p2l_w1,  w_p2l1, HID_, D_,   DP_);
  convert_pad<<<cgrid((size_t)H_ * HID_),  256, 0, stream>>>(p2l_w2,  w_p2l2, H_,   HID_, HID_);
  convert_pad<<<cgrid((size_t)H3_ * H_),   256, 0, stream>>>(enc_wih, w_ewih, H3_,  H_,   H_);
  convert_pad<<<cgrid((size_t)H3_ * H_),   256, 0, stream>>>(enc_whh, w_ewhh, H3_,  H_,   H_);
  convert_pad<<<cgrid((size_t)HID_ * H_),  256, 0, stream>>>(l2p_w1,  w_l2p1, HID_, H_,   H_);
  convert_pad<<<cgrid((size_t)HID_ * H_),  256, 0, stream>>>(l2s_w1,  w_l2s1, HID_, H_,   H_);

  // ---- par2lat(x) in 16384-row slabs (xb/tmpc in xpcB; consumed before producers) ----
  for (int rc = 0; rc < TB / RA; rc++) {
    { dim3 g(HID_ / 128, RA / 128);
      gemm_bt<128,128,64,64,EPI_BF16_RELU><<<g, 256, 0, stream>>>(
          xb + (size_t)rc * RA * DP_, w_p2l1, p2l_b1, tmpc, RA, HID_, DP_, 0); }
    { dim3 g(H_ / 128, RA / 128);
      gemm_bt<128,128,64,64,EPI_BF16_RELU_PERM><<<g, 256, 0, stream>>>(
          tmpc, w_p2l2, p2l_b2, latent, RA, H_, HID_, rc * RA); }
  }

  // ---- encoder: xp chunk 0 standalone, then fused launches ----
  (void)hipFuncSetAttribute((const void*)enc_fused,
                            hipFuncAttributeMaxDynamicSharedMemorySize, ENC_SMEM);
  enc_init<<<(B_ * H_) / 256, 256, 0, stream>>>(h32, bar);
  { dim3 g(H3_ / 128, (CHUNK * B_) / 128);
    gemm_bt<128,128,64,64,EPI_BF16><<<g, 256, 0, stream>>>(
        latent, w_ewih, enc_bih, xpcA, CHUNK * B_, H3_, H_, 0); }
  for (int tc = 0; tc < T_ / CHUNK; tc++) {
    bf16* cur = (tc & 1) ? xpcB : xpcA;
    bf16* nxt = (tc < 7) ? ((tc & 1) ? xpcA : xpcB) : nullptr;
    const bf16* latn = latent + (size_t)(tc + 1 < 8 ? tc + 1 : 0) * CHUNK * B_ * H_;
    const bool last = (tc == 7);
    enc_fused<<<dim3(256), dim3(256), ENC_SMEM, stream>>>(
        cur, w_ewhh, enc_bhh, enc_out, h32, bar, tc * CHUNK,
        latn, w_ewih, enc_bih, nxt,
        w_l2s1, l2s_b1, l2s_w2, part_g,
        last ? dec_wih : nullptr, last ? dec_whh : nullptr, w_dwih, w_dwhh);
  }

  // ---- attention: score for chunks 6-7 + softmax-pool ----
  score_gemm<<<dim3(4, 128), 256, 0, stream>>>(
      enc_out, w_l2s1, l2s_b1, l2s_w2, part_g, 6 * CHUNK * B_);
  attention<<<B_, 256, 0, stream>>>(part_g, enc_out, out_rep, hs32, hs16);

  // ---- decoder: weights already converted (enc tc=7); 10 autoregressive steps ----
  ppad_init<<<(B_ * DP_) / 256, 256, 0, stream>>>(x, ppad);
  for (int s = 0; s < NPRED; s++) {
    { dim3 g(HID_ / 128, B_ / 64);
      gemm_bt<64,128,32,64,EPI_BF16_RELU><<<g, 256, 0, stream>>>(ppad, w_p2l1, p2l_b1, d1, B_, HID_, DP_, 0); }
    { dim3 g(H_ / 128, B_ / 64);
      gemm_bt<64,128,32,64,EPI_BF16_RELU><<<g, 256, 0, stream>>>(d1, w_p2l2, p2l_b2, inp, B_, H_, HID_, 0); }
    { dim3 g(H3_ / 128, B_ / 64, 2);
      gemm_bt_dual<<<g, 256, 0, stream>>>(inp, w_dwih, dec_bih, gib,
                                          hs16, w_dwhh, dec_bhh, ghb, B_, H3_, H_); }
    dec_gates<<<(B_ * H_) / 256, 256, 0, stream>>>(gib, ghb, hs32, hs16);
    { dim3 g(HID_ / 128, B_ / 64);
      gemm_bt<64,128,32,64,EPI_BF16_RELU><<<g, 256, 0, stream>>>(hs16, w_l2p1, l2p_b1, e1, B_, HID_, H_, 0); }
    pred_k<<<B_, 256, 0, stream>>>(e1, l2p_w2, l2p_b2, out_preds, ppad, s);
  }
}